// Round 10
// baseline (194.332 us; speedup 1.0000x reference)
//
#include <hip/hip_runtime.h>

#define BATCH   8
#define HW      (1024 * 1024)
#define NA      512
#define EPSV    1e-8f
#define LAML    0.01f
#define LAMS    0.01f

#define BPB      128                        // blocks per batch
#define NBLOCKS  (BATCH * BPB)              // 1024 = exactly 4 blocks/CU
#define PIXB     (HW / BPB)                 // 8192 pixels per block
#define UNROLL   8                          // float4 groups per thread (32 px)

#define NCOPY    16                         // privatized bin columns (32 KB LDS)
#define SCALE    4194304.0f                 // 2^22 fixed-point scale
#define INVSCALE (1.0f / 4194304.0f)
// packed word: (admin_id << 23) | q22(score);  score < 1.0201 -> q22 < 2^23

typedef unsigned long long u64;

// Single fused kernel. All 1024 blocks are co-resident by construction
// (4/CU: LDS 32KB*4=128<=160KB, 128 VGPR cap, 16 waves/CU), so a spin
// barrier on a per-batch counter is safe.
__global__ __launch_bounds__(256, 4)
void k_fused(const float* __restrict__ lights,
             const float* __restrict__ settle,
             const int*   __restrict__ admin,
             const float* __restrict__ census,
             u64*         __restrict__ gsum,      // BATCH*NA u64, zeroed
             unsigned*    __restrict__ ctr,       // BATCH u32, zeroed
             float*       __restrict__ out) {
    __shared__ unsigned int bins[NA * NCOPY];     // 32 KB; reused as lfac
    float* lfac = (float*)bins;

    const int tid = threadIdx.x;
    const int b   = blockIdx.x >> 7;              // / BPB

    #pragma unroll
    for (int i = tid; i < NA * NCOPY; i += 256) bins[i] = 0u;
    __syncthreads();

    const long base = (long)blockIdx.x * PIXB;
    const float4* __restrict__ L4 = (const float4*)(lights + base);
    const float4* __restrict__ S4 = (const float4*)(settle + base);
    const int4*   __restrict__ A4 = (const int4*)(admin + base);

    float4 l[UNROLL], s[UNROLL];
    int4   a[UNROLL];
    #pragma unroll
    for (int u = 0; u < UNROLL; ++u) {
        const int v = tid + u * 256;
        l[u] = L4[v];
        s[u] = S4[v];
        a[u] = A4[v];
    }

    // quantize scores; pk keeps (admin,score) in registers for phase 3
    uint4 pk[UNROLL];
    const int c = tid & (NCOPY - 1);
    #pragma unroll
    for (int u = 0; u < UNROLL; ++u) {
        const unsigned qx = (unsigned)((l[u].x + LAML) * (s[u].x + LAMS) * SCALE + 0.5f);
        const unsigned qy = (unsigned)((l[u].y + LAML) * (s[u].y + LAMS) * SCALE + 0.5f);
        const unsigned qz = (unsigned)((l[u].z + LAML) * (s[u].z + LAMS) * SCALE + 0.5f);
        const unsigned qw = (unsigned)((l[u].w + LAML) * (s[u].w + LAMS) * SCALE + 0.5f);
        pk[u].x = ((unsigned)a[u].x << 23) | qx;
        pk[u].y = ((unsigned)a[u].y << 23) | qy;
        pk[u].z = ((unsigned)a[u].z << 23) | qz;
        pk[u].w = ((unsigned)a[u].w << 23) | qw;
        atomicAdd(&bins[a[u].x * NCOPY + c], qx);
        atomicAdd(&bins[a[u].y * NCOPY + c], qy);
        atomicAdd(&bins[a[u].z * NCOPY + c], qz);
        atomicAdd(&bins[a[u].w * NCOPY + c], qw);
    }
    __syncthreads();

    // flush block partials: u64 integer atomics (native, fire-and-forget)
    for (int i = tid; i < NA; i += 256) {
        u64 t = 0;
        #pragma unroll
        for (int k = 0; k < NCOPY; ++k) t += bins[i * NCOPY + k];
        atomicAdd(&gsum[b * NA + i], t);
    }
    __syncthreads();                               // drains the atomics (vmcnt 0)

    // grid barrier (per batch): last of the 128 blocks releases everyone
    if (tid == 0) {
        __threadfence();
        atomicAdd(&ctr[b], 1u);
        while (__hip_atomic_load(&ctr[b], __ATOMIC_RELAXED,
                                 __HIP_MEMORY_SCOPE_AGENT) < (unsigned)BPB)
            __builtin_amdgcn_s_sleep(8);
    }
    __syncthreads();
    __threadfence();

    // phase 3: rebuild factor table (bins LDS reused), scale register scores
    for (int i = tid; i < NA; i += 256) {
        u64 t = __hip_atomic_load(&gsum[b * NA + i], __ATOMIC_RELAXED,
                                  __HIP_MEMORY_SCOPE_AGENT);
        lfac[i] = census[i] / ((float)t * INVSCALE + EPSV);
    }
    __syncthreads();

    float4* __restrict__ O4 = (float4*)(out + base);
    #pragma unroll
    for (int u = 0; u < UNROLL; ++u) {
        float4 o;
        o.x = (float)(pk[u].x & 0x7FFFFFu) * INVSCALE * lfac[pk[u].x >> 23];
        o.y = (float)(pk[u].y & 0x7FFFFFu) * INVSCALE * lfac[pk[u].y >> 23];
        o.z = (float)(pk[u].z & 0x7FFFFFu) * INVSCALE * lfac[pk[u].z >> 23];
        o.w = (float)(pk[u].w & 0x7FFFFFu) * INVSCALE * lfac[pk[u].w >> 23];
        O4[tid + u * 256] = o;
    }
}

extern "C" void kernel_launch(void* const* d_in, const int* in_sizes, int n_in,
                              void* d_out, int out_size, void* d_ws, size_t ws_size,
                              hipStream_t stream) {
    const float* lights = (const float*)d_in[0];
    const float* settle = (const float*)d_in[1];
    const int*   admin  = (const int*)d_in[2];
    const float* census = (const float*)d_in[3];
    float*       out    = (float*)d_out;

    u64*      gsum = (u64*)d_ws;                      // BATCH*NA u64 = 32 KB
    unsigned* ctr  = (unsigned*)((char*)d_ws + BATCH * NA * sizeof(u64));

    // ws is poisoned once and never re-poisoned: zero gsum + ctr every call.
    hipMemsetAsync(d_ws, 0, BATCH * NA * sizeof(u64) + BATCH * sizeof(unsigned),
                   stream);

    k_fused<<<NBLOCKS, 256, 0, stream>>>(lights, settle, admin, census,
                                         gsum, ctr, out);
}

// Round 11
// 79.669 us; speedup vs baseline: 2.4392x; 2.4392x over previous
//
#include <hip/hip_runtime.h>

#define BATCH   8
#define HW      (1024 * 1024)
#define NA      512
#define EPSV    1e-8f
#define LAML    0.01f
#define LAMS    0.01f

#define BPB      128                        // blocks per batch
#define NBLOCKS  (BATCH * BPB)              // 1024 = exactly 4 blocks/CU
#define PIXB     (HW / BPB)                 // 8192 pixels per block
#define UNROLL   8                          // float4 groups per thread (32 px)

#define NCOPY    16                         // privatized bin columns (32 KB LDS)
#define SCALE    4194304.0f                 // 2^22 fixed-point scale
#define INVSCALE (1.0f / 4194304.0f)
// packed word: (admin_id << 23) | q22(score);  score < 1.0201 -> q22 < 2^23

#define PAD      64                         // u32 words: 256 B per batch slot

typedef unsigned long long u64;

// Single fused kernel. All 1024 blocks co-resident by construction
// (4/CU: 32KB LDS*4=128<=160KB, 128 VGPR cap, 16 waves/CU <= 32).
// Barrier: arrival counter (RMW line) and release flag (write-once line)
// are SEPARATE, per-batch 256B-padded -> no RMW starvation by pollers.
__global__ __launch_bounds__(256, 4)
void k_fused(const float* __restrict__ lights,
             const float* __restrict__ settle,
             const int*   __restrict__ admin,
             const float* __restrict__ census,
             u64*         __restrict__ gsum,      // BATCH*NA u64, zeroed
             unsigned*    __restrict__ ctr,       // BATCH*PAD u32, zeroed
             unsigned*    __restrict__ flag,      // BATCH*PAD u32, zeroed
             float*       __restrict__ out) {
    __shared__ unsigned int bins[NA * NCOPY];     // 32 KB; reused as lfac
    float* lfac = (float*)bins;

    const int tid = threadIdx.x;
    const int b   = blockIdx.x >> 7;              // / BPB

    #pragma unroll
    for (int i = tid; i < NA * NCOPY; i += 256) bins[i] = 0u;
    __syncthreads();

    const long base = (long)blockIdx.x * PIXB;
    const float4* __restrict__ L4 = (const float4*)(lights + base);
    const float4* __restrict__ S4 = (const float4*)(settle + base);
    const int4*   __restrict__ A4 = (const int4*)(admin + base);

    float4 l[UNROLL], s[UNROLL];
    int4   a[UNROLL];
    #pragma unroll
    for (int u = 0; u < UNROLL; ++u) {
        const int v = tid + u * 256;
        l[u] = L4[v];
        s[u] = S4[v];
        a[u] = A4[v];
    }

    // quantize scores; pk keeps (admin,score) in registers for phase 3
    uint4 pk[UNROLL];
    const int c = tid & (NCOPY - 1);
    #pragma unroll
    for (int u = 0; u < UNROLL; ++u) {
        const unsigned qx = (unsigned)((l[u].x + LAML) * (s[u].x + LAMS) * SCALE + 0.5f);
        const unsigned qy = (unsigned)((l[u].y + LAML) * (s[u].y + LAMS) * SCALE + 0.5f);
        const unsigned qz = (unsigned)((l[u].z + LAML) * (s[u].z + LAMS) * SCALE + 0.5f);
        const unsigned qw = (unsigned)((l[u].w + LAML) * (s[u].w + LAMS) * SCALE + 0.5f);
        pk[u].x = ((unsigned)a[u].x << 23) | qx;
        pk[u].y = ((unsigned)a[u].y << 23) | qy;
        pk[u].z = ((unsigned)a[u].z << 23) | qz;
        pk[u].w = ((unsigned)a[u].w << 23) | qw;
        atomicAdd(&bins[a[u].x * NCOPY + c], qx);
        atomicAdd(&bins[a[u].y * NCOPY + c], qy);
        atomicAdd(&bins[a[u].z * NCOPY + c], qz);
        atomicAdd(&bins[a[u].w * NCOPY + c], qw);
    }
    __syncthreads();

    // flush block partials: u64 integer atomics, coalesced addresses
    for (int i = tid; i < NA; i += 256) {
        u64 t = 0;
        #pragma unroll
        for (int k = 0; k < NCOPY; ++k) t += bins[i * NCOPY + k];
        atomicAdd(&gsum[b * NA + i], t);
    }
    __syncthreads();

    // per-batch grid barrier: ACQ_REL arrival carries gsum visibility;
    // pollers read only the write-once flag line.
    if (tid == 0) {
        unsigned prev = __hip_atomic_fetch_add(&ctr[b * PAD], 1u,
                                               __ATOMIC_ACQ_REL,
                                               __HIP_MEMORY_SCOPE_AGENT);
        if (prev == (unsigned)(BPB - 1)) {
            __hip_atomic_store(&flag[b * PAD], 1u, __ATOMIC_RELEASE,
                               __HIP_MEMORY_SCOPE_AGENT);
        } else {
            while (__hip_atomic_load(&flag[b * PAD], __ATOMIC_ACQUIRE,
                                     __HIP_MEMORY_SCOPE_AGENT) == 0u)
                __builtin_amdgcn_s_sleep(32);
        }
    }
    __syncthreads();

    // phase 3: rebuild factor table (bins LDS reused), scale register scores
    for (int i = tid; i < NA; i += 256) {
        u64 t = __hip_atomic_load(&gsum[b * NA + i], __ATOMIC_RELAXED,
                                  __HIP_MEMORY_SCOPE_AGENT);
        lfac[i] = census[i] / ((float)t * INVSCALE + EPSV);
    }
    __syncthreads();

    float4* __restrict__ O4 = (float4*)(out + base);
    #pragma unroll
    for (int u = 0; u < UNROLL; ++u) {
        float4 o;
        o.x = (float)(pk[u].x & 0x7FFFFFu) * INVSCALE * lfac[pk[u].x >> 23];
        o.y = (float)(pk[u].y & 0x7FFFFFu) * INVSCALE * lfac[pk[u].y >> 23];
        o.z = (float)(pk[u].z & 0x7FFFFFu) * INVSCALE * lfac[pk[u].z >> 23];
        o.w = (float)(pk[u].w & 0x7FFFFFu) * INVSCALE * lfac[pk[u].w >> 23];
        O4[tid + u * 256] = o;
    }
}

extern "C" void kernel_launch(void* const* d_in, const int* in_sizes, int n_in,
                              void* d_out, int out_size, void* d_ws, size_t ws_size,
                              hipStream_t stream) {
    const float* lights = (const float*)d_in[0];
    const float* settle = (const float*)d_in[1];
    const int*   admin  = (const int*)d_in[2];
    const float* census = (const float*)d_in[3];
    float*       out    = (float*)d_out;

    u64*      gsum = (u64*)d_ws;                                  // 32 KB
    unsigned* ctr  = (unsigned*)((char*)d_ws + BATCH * NA * sizeof(u64));
    unsigned* flag = ctr + BATCH * PAD;

    // zero gsum + ctr + flag every call (ws poisoned once, never re-poisoned)
    size_t zbytes = BATCH * NA * sizeof(u64) + 2 * BATCH * PAD * sizeof(unsigned);
    hipMemsetAsync(d_ws, 0, zbytes, stream);

    k_fused<<<NBLOCKS, 256, 0, stream>>>(lights, settle, admin, census,
                                         gsum, ctr, flag, out);
}

// Round 12
// 64.520 us; speedup vs baseline: 3.0120x; 1.2348x over previous
//
#include <hip/hip_runtime.h>

#define BATCH   8
#define HW      (1024 * 1024)
#define NA      512
#define EPSV    1e-8f
#define LAML    0.01f
#define LAMS    0.01f

#define BPB      128                        // blocks per batch
#define NBLOCKS  (BATCH * BPB)              // 1024 = exactly 4 blocks/CU
#define PIXB     (HW / BPB)                 // 8192 pixels per block
#define UNROLL   8                          // float4 groups per thread (32 px)

#define NCOPY    16                         // privatized bin columns (32 KB LDS)
#define SCALE    4194304.0f                 // 2^22 fixed-point scale
#define INVSCALE (1.0f / 4194304.0f)
// packed word: (admin_id << 23) | q22(score);  score < 1.0201 -> q22 < 2^23

#define PAD      64                         // u32 words: 256 B per batch slot

typedef unsigned long long u64;

// Single fused kernel; 1024 blocks co-resident by construction (4/CU).
// Barrier: arrival RMW line and write-once release-flag line are separate;
// pollers use RELAXED loads (no per-poll cache invalidate) + one ACQUIRE
// after exit.
__global__ __launch_bounds__(256, 4)
void k_fused(const float* __restrict__ lights,
             const float* __restrict__ settle,
             const int*   __restrict__ admin,
             const float* __restrict__ census,
             u64*         __restrict__ gsum,      // BATCH*NA u64, zeroed
             unsigned*    __restrict__ ctr,       // BATCH*PAD u32, zeroed
             unsigned*    __restrict__ flag,      // BATCH*PAD u32, zeroed
             float*       __restrict__ out) {
    __shared__ unsigned int bins[NA * NCOPY];     // 32 KB; reused as lfac
    float* lfac = (float*)bins;

    const int tid = threadIdx.x;
    const int b   = blockIdx.x >> 7;              // / BPB

    #pragma unroll
    for (int i = tid; i < NA * NCOPY; i += 256) bins[i] = 0u;
    __syncthreads();

    const long base = (long)blockIdx.x * PIXB;
    const float4* __restrict__ L4 = (const float4*)(lights + base);
    const float4* __restrict__ S4 = (const float4*)(settle + base);
    const int4*   __restrict__ A4 = (const int4*)(admin + base);

    float4 l[UNROLL], s[UNROLL];
    int4   a[UNROLL];
    #pragma unroll
    for (int u = 0; u < UNROLL; ++u) {
        const int v = tid + u * 256;
        l[u] = L4[v];
        s[u] = S4[v];
        a[u] = A4[v];
    }
    __builtin_amdgcn_sched_barrier(0);            // keep all 24 loads in flight

    // quantize scores; pk keeps (admin,score) in registers for phase 3
    uint4 pk[UNROLL];
    const int c = tid & (NCOPY - 1);
    #pragma unroll
    for (int u = 0; u < UNROLL; ++u) {
        const unsigned qx = (unsigned)((l[u].x + LAML) * (s[u].x + LAMS) * SCALE + 0.5f);
        const unsigned qy = (unsigned)((l[u].y + LAML) * (s[u].y + LAMS) * SCALE + 0.5f);
        const unsigned qz = (unsigned)((l[u].z + LAML) * (s[u].z + LAMS) * SCALE + 0.5f);
        const unsigned qw = (unsigned)((l[u].w + LAML) * (s[u].w + LAMS) * SCALE + 0.5f);
        pk[u].x = ((unsigned)a[u].x << 23) | qx;
        pk[u].y = ((unsigned)a[u].y << 23) | qy;
        pk[u].z = ((unsigned)a[u].z << 23) | qz;
        pk[u].w = ((unsigned)a[u].w << 23) | qw;
        atomicAdd(&bins[a[u].x * NCOPY + c], qx);
        atomicAdd(&bins[a[u].y * NCOPY + c], qy);
        atomicAdd(&bins[a[u].z * NCOPY + c], qz);
        atomicAdd(&bins[a[u].w * NCOPY + c], qw);
    }
    __syncthreads();

    // flush block partials: u64 integer atomics, coalesced addresses
    for (int i = tid; i < NA; i += 256) {
        u64 t = 0;
        #pragma unroll
        for (int k = 0; k < NCOPY; ++k) t += bins[i * NCOPY + k];
        atomicAdd(&gsum[b * NA + i], t);
    }
    __syncthreads();

    // per-batch grid barrier
    if (tid == 0) {
        unsigned prev = __hip_atomic_fetch_add(&ctr[b * PAD], 1u,
                                               __ATOMIC_ACQ_REL,
                                               __HIP_MEMORY_SCOPE_AGENT);
        if (prev == (unsigned)(BPB - 1)) {
            __hip_atomic_store(&flag[b * PAD], 1u, __ATOMIC_RELEASE,
                               __HIP_MEMORY_SCOPE_AGENT);
        } else {
            // cheap relaxed polling (no cache-invalidate per iteration)
            while (__hip_atomic_load(&flag[b * PAD], __ATOMIC_RELAXED,
                                     __HIP_MEMORY_SCOPE_AGENT) == 0u)
                __builtin_amdgcn_s_sleep(16);
            // one acquire to order subsequent gsum reads
            (void)__hip_atomic_load(&flag[b * PAD], __ATOMIC_ACQUIRE,
                                    __HIP_MEMORY_SCOPE_AGENT);
        }
    }
    __syncthreads();

    // phase 3: rebuild factor table (bins LDS reused), scale register scores
    for (int i = tid; i < NA; i += 256) {
        u64 t = __hip_atomic_load(&gsum[b * NA + i], __ATOMIC_RELAXED,
                                  __HIP_MEMORY_SCOPE_AGENT);
        lfac[i] = census[i] / ((float)t * INVSCALE + EPSV);
    }
    __syncthreads();

    float4* __restrict__ O4 = (float4*)(out + base);
    #pragma unroll
    for (int u = 0; u < UNROLL; ++u) {
        float4 o;
        o.x = (float)(pk[u].x & 0x7FFFFFu) * INVSCALE * lfac[pk[u].x >> 23];
        o.y = (float)(pk[u].y & 0x7FFFFFu) * INVSCALE * lfac[pk[u].y >> 23];
        o.z = (float)(pk[u].z & 0x7FFFFFu) * INVSCALE * lfac[pk[u].z >> 23];
        o.w = (float)(pk[u].w & 0x7FFFFFu) * INVSCALE * lfac[pk[u].w >> 23];
        O4[tid + u * 256] = o;
    }
}

extern "C" void kernel_launch(void* const* d_in, const int* in_sizes, int n_in,
                              void* d_out, int out_size, void* d_ws, size_t ws_size,
                              hipStream_t stream) {
    const float* lights = (const float*)d_in[0];
    const float* settle = (const float*)d_in[1];
    const int*   admin  = (const int*)d_in[2];
    const float* census = (const float*)d_in[3];
    float*       out    = (float*)d_out;

    u64*      gsum = (u64*)d_ws;                                  // 32 KB
    unsigned* ctr  = (unsigned*)((char*)d_ws + BATCH * NA * sizeof(u64));
    unsigned* flag = ctr + BATCH * PAD;

    // zero gsum + ctr + flag every call (ws poisoned once, never re-poisoned)
    size_t zbytes = BATCH * NA * sizeof(u64) + 2 * BATCH * PAD * sizeof(unsigned);
    hipMemsetAsync(d_ws, 0, zbytes, stream);

    k_fused<<<NBLOCKS, 256, 0, stream>>>(lights, settle, admin, census,
                                         gsum, ctr, flag, out);
}